// Round 15
// baseline (21152.061 us; speedup 1.0000x reference)
//
#include <hip/hip_runtime.h>
#include <cstdint>
#include <cstddef>

#define B_  32
#define T_  64
#define D_  512
#define H_  512
#define V_  32000
#define GATES 2048

// ---------------- module-global scratch ---------------------------------------
__device__ float g_h[2][2 * B_ * H_];        // ping-pong [slot][layer*B*H]
__device__ float g_c[2][2 * B_ * H_];
__device__ int   g_fin[2][B_];               // finished flag, parity by t&1 (R6 scheme)
__device__ unsigned long long g_best2[2][B_][8];  // packed argmax, parity x 8 slots
__device__ unsigned int g_cnt[125];          // monotonic per-vt arrival counters
__device__ float g_wT[125 * 512 * 256];      // fc_w^T blocked: [vt][k][vl] (vt=256 v)
__device__ float g_wLT[2][1024 * 2048];      // per layer [k][gate*512+j], k=[x;h]
__device__ float g_part0[16][B_][GATES];     // L0 partials: 16 x 64-k slices
__device__ float g_part1[24][B_][GATES];     // L1: x slots 0..15 (32-k), h slots 16..23 (64-k)
__device__ float g_lpart[8][B_][V_];         // logits k-split partials (64-k slices)

// ---------------- Threefry-2x32 (20 rounds), exact JAX schedule ----------------
__host__ __device__ __forceinline__ void threefry2x32(uint32_t k0, uint32_t k1,
                                                      uint32_t x0, uint32_t x1,
                                                      uint32_t& o0, uint32_t& o1) {
  uint32_t kx = k0 ^ k1 ^ 0x1BD11BDAu;
  x0 += k0; x1 += k1;
#define RND(r) { x0 += x1; x1 = (x1 << (r)) | (x1 >> (32 - (r))); x1 ^= x0; }
  RND(13) RND(15) RND(26) RND(6)  x0 += k1; x1 += kx + 1u;
  RND(17) RND(29) RND(16) RND(24) x0 += kx; x1 += k0 + 2u;
  RND(13) RND(15) RND(26) RND(6)  x0 += k0; x1 += k1 + 3u;
  RND(17) RND(29) RND(16) RND(24) x0 += k1; x1 += kx + 4u;
  RND(13) RND(15) RND(26) RND(6)  x0 += kx; x1 += k0 + 5u;
#undef RND
  o0 = x0; o1 = x1;
}

__device__ __forceinline__ float gumbel_from_u32(uint32_t bits) {
  float f = __uint_as_float((bits >> 9) | 0x3f800000u) - 1.0f;   // [0,1)
  const float TINY = 1.1754943508222875e-38f;
  float u = f * (1.0f - TINY) + TINY;
  u = fmaxf(u, TINY);
  return -logf(-logf(u));
}

__device__ __forceinline__ int unpack_v(unsigned long long bb) {
  int v = (int)(0xFFFFFFFFu - (uint32_t)(bb & 0xFFFFFFFFu));
  if (v < 0) v = 0;
  if (v >= V_) v = V_ - 1;
  return v;
}

__device__ __forceinline__ unsigned long long ullmax(unsigned long long a,
                                                     unsigned long long b) {
  return a > b ? a : b;
}

// ---------------- init ---------------------------------------------------------
__global__ void init_kernel(const float* __restrict__ h_enc,
                            const float* __restrict__ c_enc) {
  int i = blockIdx.x * 256 + threadIdx.x;
  if (i < 2 * B_ * H_) { g_h[0][i] = h_enc[i]; g_c[0][i] = c_enc[i]; }
  if (i < B_) { g_fin[0][i] = 0; g_fin[1][i] = 0; }
  if (i < 2 * B_ * 8) ((unsigned long long*)g_best2)[i] = 0ull;
  if (i < 125) g_cnt[i] = 0u;
}

// ---------------- one-time weight transpose (64x64 LDS-tiled, coalesced) -------
// which==0: fc_w [32000][512] -> blocked g_wT[vt][k][vl]   (vt = v>>8, vl = v&255)
// which>=1: [R][512] -> [512][R] plain transpose into g_wLT slices.
__global__ void transpose_kernel(const float* __restrict__ src, int R, int which) {
  float* dst;
  switch (which) {
    case 0:  dst = g_wT; break;
    case 1:  dst = g_wLT[0]; break;
    case 2:  dst = g_wLT[0] + 512 * 2048; break;
    case 3:  dst = g_wLT[1]; break;
    default: dst = g_wLT[1] + 512 * 2048; break;
  }
  __shared__ float tile[64][65];
  const int r0 = blockIdx.x * 64;
  const int c0 = blockIdx.y * 64;
  const int tx = threadIdx.x & 63;
  const int ty = threadIdx.x >> 6;          // 0..3
#pragma unroll
  for (int i = 0; i < 16; ++i) {
    const int row = ty + 4 * i;
    tile[row][tx] = src[(size_t)(r0 + row) * 512 + c0 + tx];
  }
  __syncthreads();
#pragma unroll
  for (int i = 0; i < 16; ++i) {
    const int row = ty + 4 * i;
    const int k = c0 + row, v = r0 + tx;
    if (which == 0) {
      dst[(size_t)(v >> 8) * (512 * 256) + (size_t)k * 256 + (v & 255)] =
          tile[tx][row];
    } else {
      dst[(size_t)k * R + v] = tile[tx][row];
    }
  }
}

// ---------------- helpers ------------------------------------------------------
// Stage PER floats per thread from row[...] into transposed LDS zs[k][32].
template<int PER>
__device__ __forceinline__ void stage_t(float* __restrict__ zs,
                                        const float* __restrict__ row,
                                        int kq, int b) {
#pragma unroll
  for (int i = 0; i < PER; i += 4) {
    const float4 v = *(const float4*)&row[kq * PER + i];
    const int kk = kq * PER + i;
    zs[(kk + 0) * 32 + b] = v.x;
    zs[(kk + 1) * 32 + b] = v.y;
    zs[(kk + 2) * 32 + b] = v.z;
    zs[(kk + 3) * 32 + b] = v.w;
  }
}

// Gate-matmul partial, 1 col/thread: thread owns column (j0+tid), all 32 b,
// KS k's. wcol/pout are pre-offset by (j0+tid); per-output k-summation order
// is ascending k — identical across all variants -> bitwise-same partials.
template<int KS>
__device__ __forceinline__ void mm_part1(const float* __restrict__ wcol,
                                         float* __restrict__ pout,   // +[b*2048]
                                         const float* __restrict__ zs) {
  float acc[32];
#pragma unroll
  for (int b = 0; b < 32; ++b) acc[b] = 0.f;
#pragma unroll 4
  for (int k = 0; k < KS; ++k) {
    const float w = wcol[(size_t)k * GATES];
    const float4* z4 = (const float4*)&zs[k * 32];
#pragma unroll
    for (int bq = 0; bq < 8; ++bq) {
      const float4 z = z4[bq];
      acc[bq * 4 + 0] += w * z.x;
      acc[bq * 4 + 1] += w * z.y;
      acc[bq * 4 + 2] += w * z.z;
      acc[bq * 4 + 3] += w * z.w;
    }
  }
#pragma unroll
  for (int b = 0; b < 32; ++b) pout[(size_t)b * GATES] = acc[b];
}

// ---------------- K1: L0 full gates partial + L1 h-part partial ----------------
// grid 384 x 128 thr (was 192 x 256): blocks 0..255: L0 (ks=blk>>4 in 0..15,
// jt=blk&15, 128 j each). blocks 256..383: L1 h-part (ks 0..7, jt 0..15 ->
// slots 16+ks). Finer j-split doubles CU coverage again (R14's proven lever);
// per-thread work unchanged; per-output summation order unchanged.
// Token consume / fin / reset verbatim (blk==0 is ks0,jt0, x-source).
__global__ __launch_bounds__(128) void parts_a_kernel(
    int cur, int t, const float* __restrict__ input_seq,
    const float* __restrict__ embed, float* __restrict__ out_tokens) {
  __shared__ __align__(16) float zs[64 * 32];
  __shared__ int stok[B_];
  const int tid = threadIdx.x;
  const int blk = blockIdx.x;
  const int b = tid >> 2, kq = tid & 3;          // staging map (PER=16)

  if (blk < 256) {
    const int ks = blk >> 4, jt = blk & 15;
    const int k0 = ks * 64, j0 = jt * 128;
    if (k0 < 512) {
      // ---- x source ----
      if (t == 0) {
        const float* row = &input_seq[(size_t)b * (T_ * D_)];   // input_seq[b][0][:]
        stage_t<16>(zs, row + k0, kq, b);
      } else {
        if (tid < B_) {
          const int ps = (t - 1) & 1;
          unsigned long long m = 0ull;
#pragma unroll
          for (int s = 0; s < 8; ++s) m = ullmax(m, g_best2[ps][tid][s]);
          int v = unpack_v(m);
          int fin = g_fin[(t + 1) & 1][tid];       // fin_{t-1}
          int tok = fin ? 0 : v;                   // PAD=0
          stok[tid] = tok;
          if (blk == 0) {
            out_tokens[(size_t)tid * T_ + (t - 1)] = (float)tok;
            g_fin[t & 1][tid] = fin | (v == 3 ? 1 : 0);   // EOS=3
          }
        }
        if (blk == 0)                              // reset THIS step's argmax buf
          for (int i = tid; i < 2 * B_ * 8 / 2; i += 128)   // 256 entries
            g_best2[t & 1][i >> 3][i & 7] = 0ull;
        __syncthreads();
        const float* row = &embed[(size_t)stok[b] * D_];
        stage_t<16>(zs, row + k0, kq, b);
      }
    } else {
      // ---- h0_prev source ----
      const float* row = &g_h[cur][0 * B_ * H_ + b * H_];
      stage_t<16>(zs, row + (k0 - 512), kq, b);
    }
    __syncthreads();
    mm_part1<64>(&g_wLT[0][(size_t)k0 * GATES + j0 + tid],
                 &g_part0[ks][0][j0 + tid], zs);
  } else {
    const int bb2 = blk - 256;
    const int ks = bb2 >> 4, jt = bb2 & 15;
    const int k0 = ks * 64, j0 = jt * 128;
    const float* row = &g_h[cur][1 * B_ * H_ + b * H_];          // h1_prev
    stage_t<16>(zs, row + k0, kq, b);
    __syncthreads();
    mm_part1<64>(&g_wLT[1][(size_t)(512 + k0) * GATES + j0 + tid],
                 &g_part1[16 + ks][0][j0 + tid], zs);
  }
}

// ---------------- K2: finish layer 0 (fused) + L1 x-part (verbatim R14) --------
// grid 128 = ks(16) x jt(8). Block computes the h0' slice [32 b][k0..k0+32)
// directly from g_part0 (same summation order -> bitwise identical), jt==0
// writes canonical h0'/c0', then l1x mm_part1<32> (256 j).
__global__ __launch_bounds__(256) void finish0_l1x_kernel(
    int cur, const float* __restrict__ bih, const float* __restrict__ bhh) {
  __shared__ __align__(16) float zs[32 * 32];    // h0' transposed [k_local][b]
  const int tid = threadIdx.x;
  const int ks = blockIdx.x >> 3, jt = blockIdx.x & 7;
  const int k0 = ks * 32, j0 = jt * 256;

#pragma unroll
  for (int i = 0; i < 4; ++i) {
    const int idx = tid + i * 256;               // 0..1023
    const int b = idx >> 5, jl = idx & 31;
    const int j = k0 + jl;
    float gi = 0.f, gf = 0.f, gg = 0.f, go = 0.f;
    for (int s = 0; s < 16; ++s) {
      const float* p = &g_part0[s][b][0];
      gi += p[j];
      gf += p[512 + j];
      gg += p[1024 + j];
      go += p[1536 + j];
    }
    gi += bih[j]        + bhh[j];
    gf += bih[512 + j]  + bhh[512 + j];
    gg += bih[1024 + j] + bhh[1024 + j];
    go += bih[1536 + j] + bhh[1536 + j];

    const float c0v = g_c[cur][0 * B_ * H_ + b * H_ + j];
    const float si = 1.f / (1.f + expf(-gi));
    const float sf = 1.f / (1.f + expf(-gf));
    const float so = 1.f / (1.f + expf(-go));
    const float cn = sf * c0v + si * tanhf(gg);
    const float hn = so * tanhf(cn);
    zs[jl * 32 + b] = hn;
    if (jt == 0) {
      g_c[cur ^ 1][0 * B_ * H_ + b * H_ + j] = cn;
      g_h[cur ^ 1][0 * B_ * H_ + b * H_ + j] = hn;
    }
  }
  __syncthreads();
  mm_part1<32>(&g_wLT[1][(size_t)k0 * GATES + j0 + tid],
               &g_part1[ks][0][j0 + tid], zs);
}

// ---------------- K3: finish layer 1: sum 24 slots + activations (verbatim R14)-
__global__ void lstm_finish_kernel(int cur, int layer, int nslots,
                                   const float* __restrict__ bih,
                                   const float* __restrict__ bhh) {
  const int gid = blockIdx.x * 128 + threadIdx.x;
  const int b = gid >> 9, j = gid & 511;
  const float* P = (layer == 0) ? &g_part0[0][0][0] : &g_part1[0][0][0];
  float gi = 0.f, gf = 0.f, gg = 0.f, go = 0.f;
  for (int s = 0; s < nslots; ++s) {
    const float* p = P + (size_t)s * B_ * GATES + (size_t)b * GATES;
    gi += p[j];
    gf += p[512 + j];
    gg += p[1024 + j];
    go += p[1536 + j];
  }
  gi += bih[j]        + bhh[j];
  gf += bih[512 + j]  + bhh[512 + j];
  gg += bih[1024 + j] + bhh[1024 + j];
  go += bih[1536 + j] + bhh[1536 + j];

  const float c0 = g_c[cur][layer * B_ * H_ + b * H_ + j];
  const float si = 1.f / (1.f + expf(-gi));
  const float sf = 1.f / (1.f + expf(-gf));
  const float so = 1.f / (1.f + expf(-go));
  const float cn = sf * c0 + si * tanhf(gg);
  const float hn = so * tanhf(cn);
  g_c[cur ^ 1][layer * B_ * H_ + b * H_ + j] = cn;
  g_h[cur ^ 1][layer * B_ * H_ + b * H_ + j] = hn;
}

// ---------------- K4: logits partial + last-arrival fused combine --------------
// 1000 blocks x 256 thr; compute body verbatim R9/R14 winner. After storing its
// lpart slice, each block does threadfence + atomicAdd(&g_cnt[vt]); the 8th
// arrival for a vt (no spinning -> no deadlock) runs the combine for its 256 v:
// per thread (b=tid>>3, 32-v chunk), ks 0..7 ascending sum (bitwise-identical
// to the old K5), bias, out write, threefry/gumbel/pack (verbatim), 8-lane
// shfl max, atomicMax g_best2[t&1][b][vt&7]. Standard release/acquire
// fence+atomic pattern (device scope) — no grid.sync, no post-kernel reads.
__global__ __launch_bounds__(256) void logits_part_kernel(
    int cur, int tt, const float* __restrict__ fc_b,
    float* __restrict__ out_logits, uint32_t key0, uint32_t key1) {
  __shared__ __align__(16) float hs[64 * 32];    // 8KB [k][b]
  __shared__ int slast;
  const int blk = blockIdx.x;
  const int vt = blk % 125, ks = blk / 125;      // ks 0..7
  const int tid = threadIdx.x;
  const int k0 = ks * 64;

  {
    const int b = tid >> 3, kq = tid & 7;        // 8 floats per thread
    const float* row = &g_h[cur ^ 1][B_ * H_ + b * H_];
    stage_t<8>(hs, row + k0, kq, b);
  }
  __syncthreads();

  const int vp = tid & 63, bg = tid >> 6;        // bg -> b = bg*8 .. bg*8+7
  const int vl = vp * 4;
  const float* wbase = &g_wT[(size_t)vt * (512 * 256) + (size_t)k0 * 256 + vl];

  float4 acc[8];
#pragma unroll
  for (int i = 0; i < 8; ++i) acc[i] = make_float4(0.f, 0.f, 0.f, 0.f);

#define FMA4(A, S) { A.x += w.x*(S); A.y += w.y*(S); A.z += w.z*(S); A.w += w.w*(S); }
#pragma unroll 8
  for (int k = 0; k < 64; ++k) {
    const float4 w   = *(const float4*)&wbase[(size_t)k * 256];
    const float4 zlo = *(const float4*)&hs[k * 32 + bg * 8];
    const float4 zhi = *(const float4*)&hs[k * 32 + bg * 8 + 4];
    FMA4(acc[0], zlo.x) FMA4(acc[1], zlo.y) FMA4(acc[2], zlo.z) FMA4(acc[3], zlo.w)
    FMA4(acc[4], zhi.x) FMA4(acc[5], zhi.y) FMA4(acc[6], zhi.z) FMA4(acc[7], zhi.w)
  }
#undef FMA4

  const int v = vt * 256 + vl;
#pragma unroll
  for (int i = 0; i < 8; ++i)
    *(float4*)&g_lpart[ks][bg * 8 + i][v] = acc[i];

  // ---- arrival: release lpart writes, count ----
  __threadfence();
  __syncthreads();
  if (tid == 0) {
    const unsigned int old = atomicAdd(&g_cnt[vt], 1u);
    slast = ((old & 7u) == 7u) ? 1 : 0;            // 8th arrival this step
  }
  __syncthreads();
  if (!slast) return;
  __threadfence();                                 // acquire other blocks' lpart

  // ---- combine for this vt (b = tid>>3, 32-v chunk = (tid&7)*32) ----
  const int cb = tid >> 3;                         // 0..31
  const int vb0 = vt * 256 + (tid & 7) * 32;
  unsigned long long best = 0ull;
  for (int i = 0; i < 32; i += 2) {
    const int vv = vb0 + i;
    float sx = 0.f, sy = 0.f;
#pragma unroll
    for (int s = 0; s < 8; ++s) {
      const float2 p = *(const float2*)&g_lpart[s][cb][vv];
      sx += p.x; sy += p.y;
    }
    const float l0 = sx + fc_b[vv];
    const float l1 = sy + fc_b[vv + 1];
    *(float2*)&out_logits[(size_t)(cb * T_ + tt) * V_ + vv] = make_float2(l0, l1);
    uint32_t y0, y1;
    threefry2x32(key0, key1, 0u, (uint32_t)(cb * V_ + vv), y0, y1);
    const float val0 = l0 + gumbel_from_u32(y0 ^ y1);
    threefry2x32(key0, key1, 0u, (uint32_t)(cb * V_ + vv + 1), y0, y1);
    const float val1 = l1 + gumbel_from_u32(y0 ^ y1);
    uint32_t u0 = __float_as_uint(val0);
    u0 ^= (u0 >> 31) ? 0xFFFFFFFFu : 0x80000000u;  // ordered-float map
    uint32_t u1 = __float_as_uint(val1);
    u1 ^= (u1 >> 31) ? 0xFFFFFFFFu : 0x80000000u;
    const unsigned long long p0 =
        ((unsigned long long)u0 << 32) | (unsigned long long)(0xFFFFFFFFu - (uint32_t)vv);
    const unsigned long long p1 =
        ((unsigned long long)u1 << 32) | (unsigned long long)(0xFFFFFFFFu - (uint32_t)(vv + 1));
    const unsigned long long pk = p0 > p1 ? p0 : p1;   // tie -> smaller v
    if (pk > best) best = pk;
  }
#pragma unroll
  for (int off = 1; off < 8; off <<= 1)
    best = ullmax(best, (unsigned long long)__shfl_xor(best, off, 8));
  if ((tid & 7) == 0)
    atomicMax(&g_best2[tt & 1][cb][vt & 7], best);
}

// ---------------- epilogue: finalize token for t = T-1 (verbatim R9) -----------
__global__ void finalize_kernel(float* __restrict__ out_tokens) {
  const int tid = threadIdx.x;
  if (tid < B_) {
    const int ps = (T_ - 1) & 1;                 // 1
    unsigned long long m = 0ull;
#pragma unroll
    for (int s = 0; s < 8; ++s) m = ullmax(m, g_best2[ps][tid][s]);
    const int v = unpack_v(m);
    const int fin = g_fin[(T_ + 1) & 1][tid];    // fin_{T-1}
    out_tokens[(size_t)tid * T_ + (T_ - 1)] = (float)(fin ? 0 : v);
  }
}

// ---------------- host driver -------------------------------------------------
extern "C" void kernel_launch(void* const* d_in, const int* in_sizes, int n_in,
                              void* d_out, int out_size, void* d_ws, size_t ws_size,
                              hipStream_t stream) {
  const float* input_seq = (const float*)d_in[0];
  const float* h_enc = (const float*)d_in[1];
  const float* c_enc = (const float*)d_in[2];
  const float* Wih   = (const float*)d_in[3];
  const float* Whh   = (const float*)d_in[4];
  const float* bih   = (const float*)d_in[5];
  const float* bhh   = (const float*)d_in[6];
  const float* fc_w  = (const float*)d_in[7];
  const float* fc_b  = (const float*)d_in[8];
  const float* embed = (const float*)d_in[9];
  float* out = (float*)d_out;
  float* tok_out = out + (size_t)B_ * T_ * V_;
  (void)d_ws; (void)ws_size; (void)in_sizes; (void)n_in; (void)out_size;

  init_kernel<<<128, 256, 0, stream>>>(h_enc, c_enc);

  transpose_kernel<<<dim3(500, 8), 256, 0, stream>>>(fc_w, 32000, 0);
  transpose_kernel<<<dim3(32, 8),  256, 0, stream>>>(Wih,                      2048, 1);
  transpose_kernel<<<dim3(32, 8),  256, 0, stream>>>(Whh,                      2048, 2);
  transpose_kernel<<<dim3(32, 8),  256, 0, stream>>>(Wih + (size_t)2048 * 512, 2048, 3);
  transpose_kernel<<<dim3(32, 8),  256, 0, stream>>>(Whh + (size_t)2048 * 512, 2048, 4);

  uint32_t keys[T_][2];
  for (int t = 0; t < T_; ++t)
    threefry2x32(0u, 42u, 0u, (uint32_t)t, keys[t][0], keys[t][1]);

  int cur = 0;
  for (int t = 0; t < T_; ++t) {
    parts_a_kernel<<<384, 128, 0, stream>>>(cur, t, input_seq, embed, tok_out);
    finish0_l1x_kernel<<<128, 256, 0, stream>>>(cur, bih, bhh);
    lstm_finish_kernel<<<128, 128, 0, stream>>>(cur, 1, 24, bih + 2048, bhh + 2048);
    logits_part_kernel<<<1000, 256, 0, stream>>>(cur, t, fc_b, out,
                                                 keys[t][0], keys[t][1]);
    cur ^= 1;
  }
  finalize_kernel<<<1, 64, 0, stream>>>(tok_out);
}

// Round 17
// 4951.105 us; speedup vs baseline: 4.2722x; 4.2722x over previous
//
#include <hip/hip_runtime.h>
#include <cstdint>
#include <cstddef>

#define B_  32
#define T_  64
#define D_  512
#define H_  512
#define V_  32000
#define GATES 2048

// ---------------- module-global scratch ---------------------------------------
__device__ float g_h[2][2 * B_ * H_];        // ping-pong [slot][layer*B*H]
__device__ float g_c[2][2 * B_ * H_];
__device__ int   g_fin[2][B_];               // finished flag, parity by t&1 (R6 scheme)
__device__ unsigned long long g_best2[2][B_][8];  // packed argmax, parity x 8 slots
__device__ float g_wT[125 * 512 * 256];      // fc_w^T blocked: [vt][k][vl] (vt=256 v)
__device__ float g_wLT[2][1024 * 2048];      // per layer [k][gate*512+j], k=[x;h]
__device__ float g_part0[16][B_][GATES];     // L0 partials: 16 x 64-k slices
__device__ float g_part1[24][B_][GATES];     // L1: x slots 0..15 (32-k), h slots 16..23 (64-k)
__device__ float g_lpart[8][B_][V_];         // logits k-split partials (64-k slices)

// ---------------- Threefry-2x32 (20 rounds), exact JAX schedule ----------------
__host__ __device__ __forceinline__ void threefry2x32(uint32_t k0, uint32_t k1,
                                                      uint32_t x0, uint32_t x1,
                                                      uint32_t& o0, uint32_t& o1) {
  uint32_t kx = k0 ^ k1 ^ 0x1BD11BDAu;
  x0 += k0; x1 += k1;
#define RND(r) { x0 += x1; x1 = (x1 << (r)) | (x1 >> (32 - (r))); x1 ^= x0; }
  RND(13) RND(15) RND(26) RND(6)  x0 += k1; x1 += kx + 1u;
  RND(17) RND(29) RND(16) RND(24) x0 += kx; x1 += k0 + 2u;
  RND(13) RND(15) RND(26) RND(6)  x0 += k0; x1 += k1 + 3u;
  RND(17) RND(29) RND(16) RND(24) x0 += k1; x1 += kx + 4u;
  RND(13) RND(15) RND(26) RND(6)  x0 += kx; x1 += k0 + 5u;
#undef RND
  o0 = x0; o1 = x1;
}

__device__ __forceinline__ float gumbel_from_u32(uint32_t bits) {
  float f = __uint_as_float((bits >> 9) | 0x3f800000u) - 1.0f;   // [0,1)
  const float TINY = 1.1754943508222875e-38f;
  float u = f * (1.0f - TINY) + TINY;
  u = fmaxf(u, TINY);
  return -logf(-logf(u));
}

__device__ __forceinline__ int unpack_v(unsigned long long bb) {
  int v = (int)(0xFFFFFFFFu - (uint32_t)(bb & 0xFFFFFFFFu));
  if (v < 0) v = 0;
  if (v >= V_) v = V_ - 1;
  return v;
}

__device__ __forceinline__ unsigned long long ullmax(unsigned long long a,
                                                     unsigned long long b) {
  return a > b ? a : b;
}

// ---------------- init ---------------------------------------------------------
__global__ void init_kernel(const float* __restrict__ h_enc,
                            const float* __restrict__ c_enc) {
  int i = blockIdx.x * 256 + threadIdx.x;
  if (i < 2 * B_ * H_) { g_h[0][i] = h_enc[i]; g_c[0][i] = c_enc[i]; }
  if (i < B_) { g_fin[0][i] = 0; g_fin[1][i] = 0; }
  if (i < 2 * B_ * 8) ((unsigned long long*)g_best2)[i] = 0ull;
}

// ---------------- one-time weight transpose (64x64 LDS-tiled, coalesced) -------
// which==0: fc_w [32000][512] -> blocked g_wT[vt][k][vl]   (vt = v>>8, vl = v&255)
// which>=1: [R][512] -> [512][R] plain transpose into g_wLT slices.
__global__ void transpose_kernel(const float* __restrict__ src, int R, int which) {
  float* dst;
  switch (which) {
    case 0:  dst = g_wT; break;
    case 1:  dst = g_wLT[0]; break;
    case 2:  dst = g_wLT[0] + 512 * 2048; break;
    case 3:  dst = g_wLT[1]; break;
    default: dst = g_wLT[1] + 512 * 2048; break;
  }
  __shared__ float tile[64][65];
  const int r0 = blockIdx.x * 64;
  const int c0 = blockIdx.y * 64;
  const int tx = threadIdx.x & 63;
  const int ty = threadIdx.x >> 6;          // 0..3
#pragma unroll
  for (int i = 0; i < 16; ++i) {
    const int row = ty + 4 * i;
    tile[row][tx] = src[(size_t)(r0 + row) * 512 + c0 + tx];
  }
  __syncthreads();
#pragma unroll
  for (int i = 0; i < 16; ++i) {
    const int row = ty + 4 * i;
    const int k = c0 + row, v = r0 + tx;
    if (which == 0) {
      dst[(size_t)(v >> 8) * (512 * 256) + (size_t)k * 256 + (v & 255)] =
          tile[tx][row];
    } else {
      dst[(size_t)k * R + v] = tile[tx][row];
    }
  }
}

// ---------------- helpers ------------------------------------------------------
// Stage PER floats per thread from row[...] into transposed LDS zs[k][32].
template<int PER>
__device__ __forceinline__ void stage_t(float* __restrict__ zs,
                                        const float* __restrict__ row,
                                        int kq, int b) {
#pragma unroll
  for (int i = 0; i < PER; i += 4) {
    const float4 v = *(const float4*)&row[kq * PER + i];
    const int kk = kq * PER + i;
    zs[(kk + 0) * 32 + b] = v.x;
    zs[(kk + 1) * 32 + b] = v.y;
    zs[(kk + 2) * 32 + b] = v.z;
    zs[(kk + 3) * 32 + b] = v.w;
  }
}

// Gate-matmul partial, 1 col/thread: thread owns column (j0+tid), all 32 b,
// KS k's. wcol/pout are pre-offset by (j0+tid); per-output k-summation order
// is ascending k — identical to the old 2-col mm_part -> bitwise-same partials.
template<int KS>
__device__ __forceinline__ void mm_part1(const float* __restrict__ wcol,
                                         float* __restrict__ pout,   // +[b*2048]
                                         const float* __restrict__ zs) {
  float acc[32];
#pragma unroll
  for (int b = 0; b < 32; ++b) acc[b] = 0.f;
#pragma unroll 4
  for (int k = 0; k < KS; ++k) {
    const float w = wcol[(size_t)k * GATES];
    const float4* z4 = (const float4*)&zs[k * 32];
#pragma unroll
    for (int bq = 0; bq < 8; ++bq) {
      const float4 z = z4[bq];
      acc[bq * 4 + 0] += w * z.x;
      acc[bq * 4 + 1] += w * z.y;
      acc[bq * 4 + 2] += w * z.z;
      acc[bq * 4 + 3] += w * z.w;
    }
  }
#pragma unroll
  for (int b = 0; b < 32; ++b) pout[(size_t)b * GATES] = acc[b];
}

// ---------------- K1: L0 full gates partial + L1 h-part partial ----------------
// grid 192: blocks 0..127: L0 (ks=blk>>3 in 0..15, jt=blk&7, 256 j).
// blocks 128..191: L1 h-part (ks=bb2>>3 in 0..7, jt 0..7 -> slots 16+ks).
// Finer j-split doubles CU coverage; per-output summation order unchanged.
// Token consume / fin / reset logic verbatim R9 (blk==0 is ks0,jt0, x-source).
__global__ void parts_a_kernel(int cur, int t,
                               const float* __restrict__ input_seq,
                               const float* __restrict__ embed,
                               float* __restrict__ out_tokens) {
  __shared__ __align__(16) float zs[64 * 32];
  __shared__ int stok[B_];
  const int tid = threadIdx.x;
  const int blk = blockIdx.x;
  const int b = tid >> 3, kq = tid & 7;

  if (blk < 128) {
    const int ks = blk >> 3, jt = blk & 7;
    const int k0 = ks * 64, j0 = jt * 256;
    if (k0 < 512) {
      // ---- x source ----
      if (t == 0) {
        const float* row = &input_seq[(size_t)b * (T_ * D_)];   // input_seq[b][0][:]
        stage_t<8>(zs, row + k0, kq, b);
      } else {
        if (tid < B_) {
          const int ps = (t - 1) & 1;
          unsigned long long m = 0ull;
#pragma unroll
          for (int s = 0; s < 8; ++s) m = ullmax(m, g_best2[ps][tid][s]);
          int v = unpack_v(m);
          int fin = g_fin[(t + 1) & 1][tid];       // fin_{t-1}
          int tok = fin ? 0 : v;                   // PAD=0
          stok[tid] = tok;
          if (blk == 0) {
            out_tokens[(size_t)tid * T_ + (t - 1)] = (float)tok;
            g_fin[t & 1][tid] = fin | (v == 3 ? 1 : 0);   // EOS=3
          }
        }
        if (blk == 0)                              // reset THIS step's argmax buf
          g_best2[t & 1][tid >> 3][tid & 7] = 0ull;
        __syncthreads();
        const float* row = &embed[(size_t)stok[b] * D_];
        stage_t<8>(zs, row + k0, kq, b);
      }
    } else {
      // ---- h0_prev source ----
      const float* row = &g_h[cur][0 * B_ * H_ + b * H_];
      stage_t<8>(zs, row + (k0 - 512), kq, b);
    }
    __syncthreads();
    mm_part1<64>(&g_wLT[0][(size_t)k0 * GATES + j0 + tid],
                 &g_part0[ks][0][j0 + tid], zs);
  } else {
    const int bb2 = blk - 128;
    const int ks = bb2 >> 3, jt = bb2 & 7;
    const int k0 = ks * 64, j0 = jt * 256;
    const float* row = &g_h[cur][1 * B_ * H_ + b * H_];          // h1_prev
    stage_t<8>(zs, row + k0, kq, b);
    __syncthreads();
    mm_part1<64>(&g_wLT[1][(size_t)(512 + k0) * GATES + j0 + tid],
                 &g_part1[16 + ks][0][j0 + tid], zs);
  }
}

// ---------------- K2: finish layer 0 (fused) + L1 x-part -----------------------
// grid 128 = ks(16) x jt(8). Block computes the h0' slice [32 b][k0..k0+32)
// directly from g_part0 (same summation order -> bitwise identical), jt==0
// writes canonical h0'/c0', then l1x mm_part1<32> (256 j).
__global__ __launch_bounds__(256) void finish0_l1x_kernel(
    int cur, const float* __restrict__ bih, const float* __restrict__ bhh) {
  __shared__ __align__(16) float zs[32 * 32];    // h0' transposed [k_local][b]
  const int tid = threadIdx.x;
  const int ks = blockIdx.x >> 3, jt = blockIdx.x & 7;
  const int k0 = ks * 32, j0 = jt * 256;

#pragma unroll
  for (int i = 0; i < 4; ++i) {
    const int idx = tid + i * 256;               // 0..1023
    const int b = idx >> 5, jl = idx & 31;
    const int j = k0 + jl;
    float gi = 0.f, gf = 0.f, gg = 0.f, go = 0.f;
    for (int s = 0; s < 16; ++s) {
      const float* p = &g_part0[s][b][0];
      gi += p[j];
      gf += p[512 + j];
      gg += p[1024 + j];
      go += p[1536 + j];
    }
    gi += bih[j]        + bhh[j];
    gf += bih[512 + j]  + bhh[512 + j];
    gg += bih[1024 + j] + bhh[1024 + j];
    go += bih[1536 + j] + bhh[1536 + j];

    const float c0v = g_c[cur][0 * B_ * H_ + b * H_ + j];
    const float si = 1.f / (1.f + expf(-gi));
    const float sf = 1.f / (1.f + expf(-gf));
    const float so = 1.f / (1.f + expf(-go));
    const float cn = sf * c0v + si * tanhf(gg);
    const float hn = so * tanhf(cn);
    zs[jl * 32 + b] = hn;
    if (jt == 0) {
      g_c[cur ^ 1][0 * B_ * H_ + b * H_ + j] = cn;
      g_h[cur ^ 1][0 * B_ * H_ + b * H_ + j] = hn;
    }
  }
  __syncthreads();
  mm_part1<32>(&g_wLT[1][(size_t)k0 * GATES + j0 + tid],
               &g_part1[ks][0][j0 + tid], zs);
}

// ---------------- K3: finish layer 1: sum 24 slots + activations ---------------
// grid 128 x 128: same gid mapping as the verified 64x256 variant.
__global__ void lstm_finish_kernel(int cur, int layer, int nslots,
                                   const float* __restrict__ bih,
                                   const float* __restrict__ bhh) {
  const int gid = blockIdx.x * 128 + threadIdx.x;
  const int b = gid >> 9, j = gid & 511;
  const float* P = (layer == 0) ? &g_part0[0][0][0] : &g_part1[0][0][0];
  float gi = 0.f, gf = 0.f, gg = 0.f, go = 0.f;
  for (int s = 0; s < nslots; ++s) {
    const float* p = P + (size_t)s * B_ * GATES + (size_t)b * GATES;
    gi += p[j];
    gf += p[512 + j];
    gg += p[1024 + j];
    go += p[1536 + j];
  }
  gi += bih[j]        + bhh[j];
  gf += bih[512 + j]  + bhh[512 + j];
  gg += bih[1024 + j] + bhh[1024 + j];
  go += bih[1536 + j] + bhh[1536 + j];

  const float c0 = g_c[cur][layer * B_ * H_ + b * H_ + j];
  const float si = 1.f / (1.f + expf(-gi));
  const float sf = 1.f / (1.f + expf(-gf));
  const float so = 1.f / (1.f + expf(-go));
  const float cn = sf * c0 + si * tanhf(gg);
  const float hn = so * tanhf(cn);
  g_c[cur ^ 1][layer * B_ * H_ + b * H_ + j] = cn;
  g_h[cur ^ 1][layer * B_ * H_ + b * H_ + j] = hn;
}

// ---------------- K4: logits partial, ks8 x vt125 (verbatim R3/R9 winner) ------
// 1000 blocks x 256 thr (4 waves). Thread: float4 w (4 v) x 8 b = 32 acc.
// Wave covers 256 contiguous v (blocked wT tile -> contiguous 64KB stream/block).
__global__ __launch_bounds__(256) void logits_part_kernel(int cur) {
  __shared__ __align__(16) float hs[64 * 32];    // 8KB [k][b]
  const int blk = blockIdx.x;
  const int vt = blk % 125, ks = blk / 125;      // ks 0..7
  const int tid = threadIdx.x;
  const int k0 = ks * 64;

  {
    const int b = tid >> 3, kq = tid & 7;        // 8 floats per thread
    const float* row = &g_h[cur ^ 1][B_ * H_ + b * H_];
    stage_t<8>(hs, row + k0, kq, b);
  }
  __syncthreads();

  const int vp = tid & 63, bg = tid >> 6;        // bg -> b = bg*8 .. bg*8+7
  const int vl = vp * 4;
  const float* wbase = &g_wT[(size_t)vt * (512 * 256) + (size_t)k0 * 256 + vl];

  float4 acc[8];
#pragma unroll
  for (int i = 0; i < 8; ++i) acc[i] = make_float4(0.f, 0.f, 0.f, 0.f);

#define FMA4(A, S) { A.x += w.x*(S); A.y += w.y*(S); A.z += w.z*(S); A.w += w.w*(S); }
#pragma unroll 8
  for (int k = 0; k < 64; ++k) {
    const float4 w   = *(const float4*)&wbase[(size_t)k * 256];
    const float4 zlo = *(const float4*)&hs[k * 32 + bg * 8];
    const float4 zhi = *(const float4*)&hs[k * 32 + bg * 8 + 4];
    FMA4(acc[0], zlo.x) FMA4(acc[1], zlo.y) FMA4(acc[2], zlo.z) FMA4(acc[3], zlo.w)
    FMA4(acc[4], zhi.x) FMA4(acc[5], zhi.y) FMA4(acc[6], zhi.z) FMA4(acc[7], zhi.w)
  }
#undef FMA4

  const int v = vt * 256 + vl;
#pragma unroll
  for (int i = 0; i < 8; ++i)
    *(float4*)&g_lpart[ks][bg * 8 + i][v] = acc[i];
}

// ---------------- K5: combine + gumbel + per-b argmax (verbatim R9) ------------
// grid 512 = b(32) x vr(16, 2000 v each); 256 thr; thread handles v-pairs.
__global__ __launch_bounds__(256) void logits_combine_kernel(
    const float* __restrict__ fc_b, float* __restrict__ out_logits,
    int t, uint32_t key0, uint32_t key1) {
  __shared__ unsigned long long sv[256];
  const int b  = blockIdx.x >> 4;
  const int vr = blockIdx.x & 15;
  const int tid = threadIdx.x;
  const int vbase = vr * 2000, vend = vbase + 2000;

  unsigned long long best = 0ull;
  for (int it = 0; it < 4; ++it) {
    const int v = vbase + (it * 256 + tid) * 2;
    if (v < vend) {
      float sx = 0.f, sy = 0.f;
#pragma unroll
      for (int ks = 0; ks < 8; ++ks) {
        const float2 p = *(const float2*)&g_lpart[ks][b][v];
        sx += p.x; sy += p.y;
      }
      const float l0 = sx + fc_b[v];
      const float l1 = sy + fc_b[v + 1];
      *(float2*)&out_logits[(size_t)(b * T_ + t) * V_ + v] = make_float2(l0, l1);
      uint32_t y0, y1;
      threefry2x32(key0, key1, 0u, (uint32_t)(b * V_ + v), y0, y1);
      const float val0 = l0 + gumbel_from_u32(y0 ^ y1);
      threefry2x32(key0, key1, 0u, (uint32_t)(b * V_ + v + 1), y0, y1);
      const float val1 = l1 + gumbel_from_u32(y0 ^ y1);
      uint32_t u0 = __float_as_uint(val0);
      u0 ^= (u0 >> 31) ? 0xFFFFFFFFu : 0x80000000u;            // ordered-float map
      uint32_t u1 = __float_as_uint(val1);
      u1 ^= (u1 >> 31) ? 0xFFFFFFFFu : 0x80000000u;
      const unsigned long long p0 =
          ((unsigned long long)u0 << 32) | (unsigned long long)(0xFFFFFFFFu - (uint32_t)v);
      const unsigned long long p1 =
          ((unsigned long long)u1 << 32) | (unsigned long long)(0xFFFFFFFFu - (uint32_t)(v + 1));
      unsigned long long pk = p0 > p1 ? p0 : p1;               // tie -> smaller v
      if (pk > best) best = pk;
    }
  }
  sv[tid] = best;
  __syncthreads();
  for (int s = 128; s > 0; s >>= 1) {
    if (tid < s) { if (sv[tid + s] > sv[tid]) sv[tid] = sv[tid + s]; }
    __syncthreads();
  }
  if (tid == 0) atomicMax(&g_best2[t & 1][b][vr & 7], sv[0]);
}

// ---------------- epilogue: finalize token for t = T-1 (verbatim R9) -----------
__global__ void finalize_kernel(float* __restrict__ out_tokens) {
  const int tid = threadIdx.x;
  if (tid < B_) {
    const int ps = (T_ - 1) & 1;                 // 1
    unsigned long long m = 0ull;
#pragma unroll
    for (int s = 0; s < 8; ++s) m = ullmax(m, g_best2[ps][tid][s]);
    const int v = unpack_v(m);
    const int fin = g_fin[(T_ + 1) & 1][tid];    // fin_{T-1}
    out_tokens[(size_t)tid * T_ + (T_ - 1)] = (float)(fin ? 0 : v);
  }
}

// ---------------- host driver -------------------------------------------------
extern "C" void kernel_launch(void* const* d_in, const int* in_sizes, int n_in,
                              void* d_out, int out_size, void* d_ws, size_t ws_size,
                              hipStream_t stream) {
  const float* input_seq = (const float*)d_in[0];
  const float* h_enc = (const float*)d_in[1];
  const float* c_enc = (const float*)d_in[2];
  const float* Wih   = (const float*)d_in[3];
  const float* Whh   = (const float*)d_in[4];
  const float* bih   = (const float*)d_in[5];
  const float* bhh   = (const float*)d_in[6];
  const float* fc_w  = (const float*)d_in[7];
  const float* fc_b  = (const float*)d_in[8];
  const float* embed = (const float*)d_in[9];
  float* out = (float*)d_out;
  float* tok_out = out + (size_t)B_ * T_ * V_;
  (void)d_ws; (void)ws_size; (void)in_sizes; (void)n_in; (void)out_size;

  init_kernel<<<128, 256, 0, stream>>>(h_enc, c_enc);

  transpose_kernel<<<dim3(500, 8), 256, 0, stream>>>(fc_w, 32000, 0);
  transpose_kernel<<<dim3(32, 8),  256, 0, stream>>>(Wih,                      2048, 1);
  transpose_kernel<<<dim3(32, 8),  256, 0, stream>>>(Whh,                      2048, 2);
  transpose_kernel<<<dim3(32, 8),  256, 0, stream>>>(Wih + (size_t)2048 * 512, 2048, 3);
  transpose_kernel<<<dim3(32, 8),  256, 0, stream>>>(Whh + (size_t)2048 * 512, 2048, 4);

  uint32_t keys[T_][2];
  for (int t = 0; t < T_; ++t)
    threefry2x32(0u, 42u, 0u, (uint32_t)t, keys[t][0], keys[t][1]);

  int cur = 0;
  for (int t = 0; t < T_; ++t) {
    parts_a_kernel<<<192, 256, 0, stream>>>(cur, t, input_seq, embed, tok_out);
    finish0_l1x_kernel<<<128, 256, 0, stream>>>(cur, bih, bhh);
    lstm_finish_kernel<<<128, 128, 0, stream>>>(cur, 1, 24, bih + 2048, bhh + 2048);
    logits_part_kernel<<<1000, 256, 0, stream>>>(cur);
    logits_combine_kernel<<<512, 256, 0, stream>>>(fc_b, out, t,
                                                   keys[t][0], keys[t][1]);
    cur ^= 1;
  }
  finalize_kernel<<<1, 64, 0, stream>>>(tok_out);
}